// Round 6
// baseline (705.971 us; speedup 1.0000x reference)
//
#include <hip/hip_runtime.h>
#include <hip/hip_fp16.h>

typedef _Float16 f16;
typedef f16  f16x8 __attribute__((ext_vector_type(8)));
typedef f16  f16x4 __attribute__((ext_vector_type(4)));
typedef float f32x4 __attribute__((ext_vector_type(4)));

#define B_  4
#define T_  2048
#define D_  1024
#define H_  16
#define HD_ 64
#define M_  (B_*T_)   // 8192

__device__ __forceinline__ void gload_lds16(const void* g, void* l) {
    __builtin_amdgcn_global_load_lds((__attribute__((address_space(1))) void*)(g),
                                     (__attribute__((address_space(3))) void*)(l),
                                     16, 0, 0);
}

// ---------------- fp32 -> fp16 convert (vectorized) ----------------
__global__ __launch_bounds__(256) void cvt_f32_f16(const float* __restrict__ in,
                                                   f16* __restrict__ out, int n4) {
    int idx = blockIdx.x * blockDim.x + threadIdx.x;
    int stride = gridDim.x * blockDim.x;
    for (int i = idx; i < n4; i += stride) {
        float4 v = ((const float4*)in)[i];
        f16x4 o;
        o[0] = (f16)v.x; o[1] = (f16)v.y; o[2] = (f16)v.z; o[3] = (f16)v.w;
        ((f16x4*)out)[i] = o;
    }
}

// ---------------- transpose + convert: in [R][C] f32 -> out [C][R] f16 ----------------
__global__ __launch_bounds__(256) void transpose_cvt(const float* __restrict__ in,
                                                     f16* __restrict__ out, int R, int C) {
    __shared__ float tile[32][33];
    int bx = blockIdx.x * 32;   // col (n) base
    int by = blockIdx.y * 32;   // row (k) base
    int tx = threadIdx.x, ty = threadIdx.y;   // 32 x 8
    #pragma unroll
    for (int i = 0; i < 32; i += 8)
        tile[ty + i][tx] = in[(size_t)(by + ty + i) * C + bx + tx];
    __syncthreads();
    #pragma unroll
    for (int i = 0; i < 32; i += 8)
        out[(size_t)(bx + ty + i) * R + by + tx] = (f16)tile[tx][ty + i];
}

// ---------------- 128x128 BT-GEMM (m97 structure), K=1024 fixed ----------------
// EPI 0: scatter to Q[B,H,T,HD], K[B,H,T,HD], Vt[B,H,HD,T] (f16)
// EPI 1: plain f32 C[M][N]
template<int EPI>
__global__ __launch_bounds__(256) void gemm128(const f16* __restrict__ A,
                                               const f16* __restrict__ Bt, int N,
                                               f16* __restrict__ Qb, f16* __restrict__ Kb,
                                               f16* __restrict__ Vt, float* __restrict__ Cout) {
    __shared__ f16 At[128][32];
    __shared__ f16 Bs[128][32];
    const int tid = threadIdx.x;
    const int lane = tid & 63;
    const int w = tid >> 6;
    const int g = lane >> 4;
    const int l15 = lane & 15;
    const int wr = w >> 1, wc = w & 1;
    const int m0 = blockIdx.y * 128;
    const int n0 = blockIdx.x * 128;
    const int K = 1024;

    f32x4 acc[4][4];
    #pragma unroll
    for (int i = 0; i < 4; i++)
        #pragma unroll
        for (int j = 0; j < 4; j++)
            acc[i][j] = f32x4{0.f, 0.f, 0.f, 0.f};

    for (int k0 = 0; k0 < K; k0 += 32) {
        __syncthreads();   // WAR: previous iteration's LDS reads done
        #pragma unroll
        for (int i = 0; i < 2; i++) {
            int call = w * 2 + i;
            int chunk = call * 64 + lane;
            int r  = chunk >> 2;
            int c8 = (chunk & 3) * 8;
            gload_lds16(&A [(size_t)(m0 + r) * K + k0 + c8], ((char*)&At[0][0]) + (size_t)call * 1024);
            gload_lds16(&Bt[(size_t)(n0 + r) * K + k0 + c8], ((char*)&Bs[0][0]) + (size_t)call * 1024);
        }
        __syncthreads();   // waits vmcnt(0): tiles resident
        f16x8 a[4], b[4];
        #pragma unroll
        for (int i = 0; i < 4; i++) a[i] = *(const f16x8*)&At[wr * 64 + i * 16 + l15][g * 8];
        #pragma unroll
        for (int j = 0; j < 4; j++) b[j] = *(const f16x8*)&Bs[wc * 64 + j * 16 + l15][g * 8];
        #pragma unroll
        for (int i = 0; i < 4; i++)
            #pragma unroll
            for (int j = 0; j < 4; j++)
                acc[i][j] = __builtin_amdgcn_mfma_f32_16x16x32_f16(a[i], b[j], acc[i][j], 0, 0, 0);
    }

    if (EPI == 0) {
        const int which = n0 >> 10;              // 0:Q 1:K 2:V (128 | 1024 so uniform per block)
        const int nbase = (n0 & 1023) + wc * 64; // within-region col base
        #pragma unroll
        for (int i = 0; i < 4; i++) {
            int m = m0 + wr * 64 + i * 16 + g * 4;   // rows m..m+3 share b (128-aligned tiles)
            int bb = m >> 11;
            int t  = m & 2047;
            #pragma unroll
            for (int j = 0; j < 4; j++) {
                int n = nbase + j * 16 + l15;
                int h = n >> 6, d = n & 63;
                #pragma unroll
                for (int r = 0; r < 4; r++) {
                    f16 v = (f16)acc[i][j][r];
                    if      (which == 0) Qb[(((size_t)bb * H_ + h) * T_ + t + r) * HD_ + d] = v;
                    else if (which == 1) Kb[(((size_t)bb * H_ + h) * T_ + t + r) * HD_ + d] = v;
                    else                 Vt[(((size_t)bb * H_ + h) * HD_ + d) * T_ + t + r] = v;
                }
            }
        }
    } else {
        #pragma unroll
        for (int i = 0; i < 4; i++)
            #pragma unroll
            for (int j = 0; j < 4; j++)
                #pragma unroll
                for (int r = 0; r < 4; r++)
                    Cout[(size_t)(m0 + wr * 64 + i * 16 + g * 4 + r) * N + n0 + wc * 64 + j * 16 + l15]
                        = acc[i][j][r];
    }
}

// ---------------- causal flash attention ----------------
// grid (T/64, B*H), 256 threads. Wave w owns q-rows [q0+16w, q0+16w+16).
// Swapped QK^T: S^T[key][q] = mfma(A=K_frag, B=Q_frag). Softmax per q = col of S^T:
// local 8-val reduce + shfl_xor 16,32. P relayout via per-wave LDS. PV: O += P*V,
// V read from Vt[B,H,HD,T] (contiguous keys).
__global__ __launch_bounds__(256) void attn_fwd(const f16* __restrict__ Qb, const f16* __restrict__ Kb,
                                                const f16* __restrict__ Vt, f16* __restrict__ Yb) {
    __shared__ f16 P[4][16][32];
    const int tid = threadIdx.x;
    const int lane = tid & 63;
    const int w = tid >> 6;
    const int g = lane >> 4;
    const int l15 = lane & 15;
    const int bh = blockIdx.y;
    const int b = bh >> 4, h = bh & 15;
    const int qw = blockIdx.x * 64 + w * 16;

    const f16* Qp = Qb + ((size_t)bh * T_ + qw) * HD_;
    const f16* Kp = Kb + (size_t)bh * T_ * HD_;
    const f16* Vp = Vt + (size_t)bh * HD_ * T_;

    // Q fragments hoisted: B-operand, col=q=l15, k=d in two 32-halves
    f16x8 qf[2];
    qf[0] = *(const f16x8*)&Qp[(size_t)l15 * HD_ + g * 8];
    qf[1] = *(const f16x8*)&Qp[(size_t)l15 * HD_ + 32 + g * 8];

    f32x4 acc[4];
    #pragma unroll
    for (int j = 0; j < 4; j++) acc[j] = f32x4{0.f, 0.f, 0.f, 0.f};
    float mrow = -1e30f, lrow = 0.f;
    const float cf = 0.125f * 1.44269504088896340736f;   // scale * log2(e)
    const int q = qw + l15;
    const int kend = qw + 16;

    for (int k0 = 0; k0 < kend; k0 += 32) {
        // K fragments: A-operand, row=key_local=l15, k=d
        f16x8 kf0a = *(const f16x8*)&Kp[(size_t)(k0 + l15) * HD_ + g * 8];
        f16x8 kf0b = *(const f16x8*)&Kp[(size_t)(k0 + l15) * HD_ + 32 + g * 8];
        f16x8 kf1a = *(const f16x8*)&Kp[(size_t)(k0 + 16 + l15) * HD_ + g * 8];
        f16x8 kf1b = *(const f16x8*)&Kp[(size_t)(k0 + 16 + l15) * HD_ + 32 + g * 8];

        f32x4 z = {0.f, 0.f, 0.f, 0.f};
        f32x4 st0 = __builtin_amdgcn_mfma_f32_16x16x32_f16(kf0a, qf[0], z,   0, 0, 0);
        st0       = __builtin_amdgcn_mfma_f32_16x16x32_f16(kf0b, qf[1], st0, 0, 0, 0);
        f32x4 st1 = __builtin_amdgcn_mfma_f32_16x16x32_f16(kf1a, qf[0], z,   0, 0, 0);
        st1       = __builtin_amdgcn_mfma_f32_16x16x32_f16(kf1b, qf[1], st1, 0, 0, 0);

        // scale + causal mask; lane holds keys {k0+g*4+r, k0+16+g*4+r} for col q
        float s[8];
        #pragma unroll
        for (int r = 0; r < 4; r++) {
            int key0 = k0 + g * 4 + r;
            int key1 = key0 + 16;
            s[r]     = (key0 <= q) ? st0[r] * cf : -1e30f;
            s[4 + r] = (key1 <= q) ? st1[r] * cf : -1e30f;
        }
        float pm = s[0];
        #pragma unroll
        for (int u = 1; u < 8; u++) pm = fmaxf(pm, s[u]);
        pm = fmaxf(pm, __shfl_xor(pm, 16));
        pm = fmaxf(pm, __shfl_xor(pm, 32));
        float mnew  = fmaxf(mrow, pm);
        float alpha = exp2f(mrow - mnew);
        float p[8], ps = 0.f;
        #pragma unroll
        for (int u = 0; u < 8; u++) { p[u] = exp2f(s[u] - mnew); ps += p[u]; }
        ps += __shfl_xor(ps, 16);
        ps += __shfl_xor(ps, 32);
        lrow = lrow * alpha + ps;
        mrow = mnew;

        // P relayout through per-wave LDS (no block barrier; divergent wave trip counts)
        asm volatile("s_waitcnt lgkmcnt(0)" ::: "memory");   // WAR vs previous pa read
        #pragma unroll
        for (int t = 0; t < 2; t++)
            #pragma unroll
            for (int r = 0; r < 4; r++)
                P[w][l15][t * 16 + g * 4 + r] = (f16)p[t * 4 + r];
        asm volatile("s_waitcnt lgkmcnt(0)" ::: "memory");   // RAW: writes visible wave-wide
        f16x8 pa = *(const f16x8*)&P[w][l15][g * 8];

        // online rescale of accumulator rows (row q_local = g*4+r)
        float al[4];
        #pragma unroll
        for (int r = 0; r < 4; r++) al[r] = __shfl(alpha, g * 4 + r);
        #pragma unroll
        for (int j = 0; j < 4; j++) {
            f16x8 vf = *(const f16x8*)&Vp[(size_t)(j * 16 + l15) * T_ + k0 + g * 8];
            f32x4 aj = acc[j];
            #pragma unroll
            for (int r = 0; r < 4; r++) aj[r] *= al[r];
            acc[j] = __builtin_amdgcn_mfma_f32_16x16x32_f16(pa, vf, aj, 0, 0, 0);
        }
    }

    float li[4];
    #pragma unroll
    for (int r = 0; r < 4; r++) li[r] = __shfl(lrow, g * 4 + r);
    #pragma unroll
    for (int j = 0; j < 4; j++)
        #pragma unroll
        for (int r = 0; r < 4; r++) {
            float y = acc[j][r] / li[r];
            Yb[((size_t)b * T_ + qw + g * 4 + r) * D_ + h * HD_ + j * 16 + l15] = (f16)y;
        }
}

// ---------------- launch ----------------
extern "C" void kernel_launch(void* const* d_in, const int* in_sizes, int n_in,
                              void* d_out, int out_size, void* d_ws, size_t ws_size,
                              hipStream_t stream) {
    const float* x      = (const float*)d_in[0];
    const float* w_qkv  = (const float*)d_in[1];
    const float* w_out  = (const float*)d_in[2];
    float* out = (float*)d_out;

    char* ws = (char*)d_ws;
    f16* Xb  = (f16*)(ws);                     // [8192][1024]            16.78 MB
    f16* Wqt = (f16*)(ws + 16777216);          // [3072][1024]             6.29 MB
    f16* Wot = (f16*)(ws + 23068672);          // [1024][1024]             2.10 MB
    f16* Qb  = (f16*)(ws + 25165824);          // [B,H,T,HD]              16.78 MB
    f16* Kb  = (f16*)(ws + 41943040);          // [B,H,T,HD]              16.78 MB
    f16* Vt  = (f16*)(ws + 58720256);          // [B,H,HD,T]              16.78 MB
    f16* Yb  = (f16*)(ws + 75497472);          // [8192][1024]            16.78 MB   -> 92.3 MB total

    cvt_f32_f16<<<2048, 256, 0, stream>>>(x, Xb, (M_ * D_) / 4);
    transpose_cvt<<<dim3(3 * D_ / 32, D_ / 32), dim3(32, 8), 0, stream>>>(w_qkv, Wqt, D_, 3 * D_);
    transpose_cvt<<<dim3(D_ / 32, D_ / 32),     dim3(32, 8), 0, stream>>>(w_out, Wot, D_, D_);

    gemm128<0><<<dim3(3 * D_ / 128, M_ / 128), 256, 0, stream>>>(Xb, Wqt, 3 * D_, Qb, Kb, Vt, nullptr);
    attn_fwd<<<dim3(T_ / 64, B_ * H_), 256, 0, stream>>>(Qb, Kb, Vt, Yb);
    gemm128<1><<<dim3(D_ / 128, M_ / 128), 256, 0, stream>>>(Yb, Wot, D_, nullptr, nullptr, nullptr, out);
}

// Round 8
// 411.548 us; speedup vs baseline: 1.7154x; 1.7154x over previous
//
#include <hip/hip_runtime.h>
#include <hip/hip_fp16.h>

typedef _Float16 f16;
typedef f16  f16x8 __attribute__((ext_vector_type(8)));
typedef f16  f16x4 __attribute__((ext_vector_type(4)));
typedef float f32x4 __attribute__((ext_vector_type(4)));

#define B_  4
#define T_  2048
#define D_  1024
#define H_  16
#define HD_ 64
#define M_  (B_*T_)   // 8192

__device__ __forceinline__ void gload_lds16(const void* g, void* l) {
    __builtin_amdgcn_global_load_lds((__attribute__((address_space(1))) void*)(g),
                                     (__attribute__((address_space(3))) void*)(l),
                                     16, 0, 0);
}

// ---------------- fp32 -> fp16 convert (vectorized) ----------------
__global__ __launch_bounds__(256) void cvt_f32_f16(const float* __restrict__ in,
                                                   f16* __restrict__ out, int n4) {
    int idx = blockIdx.x * blockDim.x + threadIdx.x;
    int stride = gridDim.x * blockDim.x;
    for (int i = idx; i < n4; i += stride) {
        float4 v = ((const float4*)in)[i];
        f16x4 o;
        o[0] = (f16)v.x; o[1] = (f16)v.y; o[2] = (f16)v.z; o[3] = (f16)v.w;
        ((f16x4*)out)[i] = o;
    }
}

// ---------------- transpose + convert: in [R][C] f32 -> out [C][R] f16 ----------------
__global__ __launch_bounds__(256) void transpose_cvt(const float* __restrict__ in,
                                                     f16* __restrict__ out, int R, int C) {
    __shared__ float tile[32][33];
    int bx = blockIdx.x * 32;   // col (n) base
    int by = blockIdx.y * 32;   // row (k) base
    int tx = threadIdx.x, ty = threadIdx.y;   // 32 x 8
    #pragma unroll
    for (int i = 0; i < 32; i += 8)
        tile[ty + i][tx] = in[(size_t)(by + ty + i) * C + bx + tx];
    __syncthreads();
    #pragma unroll
    for (int i = 0; i < 32; i += 8)
        out[(size_t)(bx + ty + i) * R + by + tx] = (f16)tile[tx][ty + i];
}

// ---------------- 128x128 BT-GEMM (m97 structure), K=1024 fixed ----------------
template<int EPI>
__global__ __launch_bounds__(256) void gemm128(const f16* __restrict__ A,
                                               const f16* __restrict__ Bt, int N,
                                               f16* __restrict__ Qb, f16* __restrict__ Kb,
                                               f16* __restrict__ Vt, float* __restrict__ Cout) {
    __shared__ f16 At[128][32];
    __shared__ f16 Bs[128][32];
    const int tid = threadIdx.x;
    const int lane = tid & 63;
    const int w = tid >> 6;
    const int g = lane >> 4;
    const int l15 = lane & 15;
    const int wr = w >> 1, wc = w & 1;
    const int m0 = blockIdx.y * 128;
    const int n0 = blockIdx.x * 128;
    const int K = 1024;

    f32x4 acc[4][4];
    #pragma unroll
    for (int i = 0; i < 4; i++)
        #pragma unroll
        for (int j = 0; j < 4; j++)
            acc[i][j] = f32x4{0.f, 0.f, 0.f, 0.f};

    for (int k0 = 0; k0 < K; k0 += 32) {
        __syncthreads();
        #pragma unroll
        for (int i = 0; i < 2; i++) {
            int call = w * 2 + i;
            int chunk = call * 64 + lane;
            int r  = chunk >> 2;
            int c8 = (chunk & 3) * 8;
            gload_lds16(&A [(size_t)(m0 + r) * K + k0 + c8], ((char*)&At[0][0]) + (size_t)call * 1024);
            gload_lds16(&Bt[(size_t)(n0 + r) * K + k0 + c8], ((char*)&Bs[0][0]) + (size_t)call * 1024);
        }
        __syncthreads();
        f16x8 a[4], b[4];
        #pragma unroll
        for (int i = 0; i < 4; i++) a[i] = *(const f16x8*)&At[wr * 64 + i * 16 + l15][g * 8];
        #pragma unroll
        for (int j = 0; j < 4; j++) b[j] = *(const f16x8*)&Bs[wc * 64 + j * 16 + l15][g * 8];
        #pragma unroll
        for (int i = 0; i < 4; i++)
            #pragma unroll
            for (int j = 0; j < 4; j++)
                acc[i][j] = __builtin_amdgcn_mfma_f32_16x16x32_f16(a[i], b[j], acc[i][j], 0, 0, 0);
    }

    if (EPI == 0) {
        const int which = n0 >> 10;
        const int nbase = (n0 & 1023) + wc * 64;
        #pragma unroll
        for (int i = 0; i < 4; i++) {
            int m = m0 + wr * 64 + i * 16 + g * 4;
            int bb = m >> 11;
            int t  = m & 2047;
            #pragma unroll
            for (int j = 0; j < 4; j++) {
                int n = nbase + j * 16 + l15;
                int h = n >> 6, d = n & 63;
                #pragma unroll
                for (int r = 0; r < 4; r++) {
                    f16 v = (f16)acc[i][j][r];
                    if      (which == 0) Qb[(((size_t)bb * H_ + h) * T_ + t + r) * HD_ + d] = v;
                    else if (which == 1) Kb[(((size_t)bb * H_ + h) * T_ + t + r) * HD_ + d] = v;
                    else                 Vt[(((size_t)bb * H_ + h) * HD_ + d) * T_ + t + r] = v;
                }
            }
        }
    } else {
        #pragma unroll
        for (int i = 0; i < 4; i++)
            #pragma unroll
            for (int j = 0; j < 4; j++)
                #pragma unroll
                for (int r = 0; r < 4; r++)
                    Cout[(size_t)(m0 + wr * 64 + i * 16 + g * 4 + r) * N + n0 + wc * 64 + j * 16 + l15]
                        = acc[i][j][r];
    }
}

// ---------------- causal flash attention v2 ----------------
// grid (16, B*H) heavy-first, 256 threads. Block owns 128 q-rows; wave w owns 32
// (two 16-row subtiles). KVBLK=64, K & V^T staged in double-buffered LDS via
// global_load_lds (counted vmcnt + raw s_barrier), XOR-16B-chunk swizzle on all
// LDS tiles (128B rows). Swapped QK^T, wave-parallel online softmax, P via LDS.
__global__ __launch_bounds__(256) void attn_fwd(const f16* __restrict__ Qb, const f16* __restrict__ Kb,
                                                const f16* __restrict__ Vt, f16* __restrict__ Yb) {
    __shared__ f16 KsB[2][64][64];   // [buf][key][d]      16 KB
    __shared__ f16 VsB[2][64][64];   // [buf][d][key]      16 KB
    __shared__ f16 PsB[4][32][64];   // [wave][q][key]     16 KB
    const int tid = threadIdx.x;
    const int lane = tid & 63;
    const int w = tid >> 6;
    const int g = lane >> 4;
    const int l15 = lane & 15;
    const int l8 = l15 & 7;
    const int bh = blockIdx.y;
    const int b = bh >> 4, h = bh & 15;
    const int qbl = (int)(gridDim.x - 1) - (int)blockIdx.x;   // heavy blocks first
    const int qw = qbl * 128 + w * 32;

    const f16* Qp = Qb + (size_t)bh * T_ * HD_;
    const f16* Kp = Kb + (size_t)bh * T_ * HD_;
    const f16* Vp = Vt + (size_t)bh * HD_ * T_;

    // Q fragments (B-operand): qf[qs][dh], col=q=l15, k=d
    f16x8 qf[2][2];
    #pragma unroll
    for (int qs = 0; qs < 2; qs++)
        #pragma unroll
        for (int dh = 0; dh < 2; dh++)
            qf[qs][dh] = *(const f16x8*)&Qp[(size_t)(qw + qs * 16 + l15) * HD_ + dh * 32 + g * 8];

    f32x4 acc[2][4];
    #pragma unroll
    for (int qs = 0; qs < 2; qs++)
        #pragma unroll
        for (int j = 0; j < 4; j++) acc[qs][j] = f32x4{0.f, 0.f, 0.f, 0.f};
    float mrow[2] = {-1e30f, -1e30f}, lrow[2] = {0.f, 0.f};
    const float cf = 0.125f * 1.44269504088896340736f;   // scale * log2(e)
    const int NT = 2 * qbl + 2;                           // 64-key tiles

    // stage K[k0..k0+64) and V^T into buf; source pre-swizzled (rule #21), LDS linear
    auto STAGE = [&](int buf, int it) {
        const int k0 = it * 64;
        #pragma unroll
        for (int cc = 0; cc < 2; cc++) {
            int cb = w * 2 + cc;
            int chunk = cb * 64 + lane;
            int row = chunk >> 3;              // key (K) / d (V)
            int sc = (chunk & 7) ^ (row & 7);  // swizzled 16B chunk within 128B row
            gload_lds16(&Kp[(size_t)(k0 + row) * HD_ + sc * 8],
                        (char*)&KsB[buf][0][0] + (size_t)cb * 1024);
            gload_lds16(&Vp[(size_t)row * T_ + k0 + sc * 8],
                        (char*)&VsB[buf][0][0] + (size_t)cb * 1024);
        }
    };

    STAGE(0, 0);
    for (int it = 0; it < NT; ++it) {
        const int cur = it & 1;
        const int k0 = it * 64;
        if (it + 1 < NT) {
            STAGE(cur ^ 1, it + 1);
            asm volatile("s_waitcnt vmcnt(4)" ::: "memory");   // cur's 4 loads landed
        } else {
            asm volatile("s_waitcnt vmcnt(0)" ::: "memory");
        }
        __builtin_amdgcn_s_barrier();          // all waves' shares of cur resident
        asm volatile("" ::: "memory");

        if (k0 < qw + 32) {                    // wave-uniform: any unmasked key?
            const char* kb = (const char*)&KsB[cur][0][0];
            const char* vb = (const char*)&VsB[cur][0][0];
            char*       pb = (char*)&PsB[w][0][0];

            // S^T = K·Q^T for 64 keys x 32 q
            float s[2][16];
            #pragma unroll
            for (int kk = 0; kk < 4; kk++) {
                int row = kk * 16 + l15;       // key-local
                f16x8 kf0 = *(const f16x8*)(kb + row * 128 + ((g * 16) ^ (l8 << 4)));
                f16x8 kf1 = *(const f16x8*)(kb + row * 128 + ((64 + g * 16) ^ (l8 << 4)));
                #pragma unroll
                for (int qs = 0; qs < 2; qs++) {
                    f32x4 st = {0.f, 0.f, 0.f, 0.f};
                    st = __builtin_amdgcn_mfma_f32_16x16x32_f16(kf0, qf[qs][0], st, 0, 0, 0);
                    st = __builtin_amdgcn_mfma_f32_16x16x32_f16(kf1, qf[qs][1], st, 0, 0, 0);
                    int q = qw + qs * 16 + l15;
                    #pragma unroll
                    for (int r = 0; r < 4; r++) {
                        int key = k0 + kk * 16 + g * 4 + r;
                        s[qs][kk * 4 + r] = (key <= q) ? st[r] * cf : -1e30f;
                    }
                }
            }

            // online softmax per q-subtile (all 64 lanes busy; 2 independent chains)
            float alpha[2];
            #pragma unroll
            for (int qs = 0; qs < 2; qs++) {
                float pm = s[qs][0];
                #pragma unroll
                for (int u = 1; u < 16; u++) pm = fmaxf(pm, s[qs][u]);
                pm = fmaxf(pm, __shfl_xor(pm, 16));
                pm = fmaxf(pm, __shfl_xor(pm, 32));
                float mnew = fmaxf(mrow[qs], pm);
                alpha[qs] = exp2f(mrow[qs] - mnew);
                float ps = 0.f;
                #pragma unroll
                for (int u = 0; u < 16; u++) { s[qs][u] = exp2f(s[qs][u] - mnew); ps += s[qs][u]; }
                ps += __shfl_xor(ps, 16);
                ps += __shfl_xor(ps, 32);
                lrow[qs] = lrow[qs] * alpha[qs] + ps;
                mrow[qs] = mnew;
                // pack 4 f16 per key-subtile -> swizzled ds_write_b64
                int prow = qs * 16 + l15;
                #pragma unroll
                for (int kk = 0; kk < 4; kk++) {
                    f16x4 pk;
                    #pragma unroll
                    for (int r = 0; r < 4; r++) pk[r] = (f16)s[qs][kk * 4 + r];
                    *(f16x4*)(pb + prow * 128 + ((kk * 32 + g * 8) ^ (l8 << 4))) = pk;
                }
            }
            asm volatile("s_waitcnt lgkmcnt(0)" ::: "memory");   // wave-local P visible
            __builtin_amdgcn_sched_barrier(0);

            // P fragments (A-operand): row=q=l15, k=key
            f16x8 pa[2][2];
            #pragma unroll
            for (int qs = 0; qs < 2; qs++)
                #pragma unroll
                for (int ks = 0; ks < 2; ks++)
                    pa[qs][ks] = *(const f16x8*)(pb + (qs * 16 + l15) * 128 +
                                                 ((ks * 64 + g * 16) ^ (l8 << 4)));

            float al[2][4];
            #pragma unroll
            for (int qs = 0; qs < 2; qs++)
                #pragma unroll
                for (int r = 0; r < 4; r++) al[qs][r] = __shfl(alpha[qs], g * 4 + r);

            #pragma unroll
            for (int j = 0; j < 4; j++) {
                f16x8 vf0 = *(const f16x8*)(vb + (j * 16 + l15) * 128 + ((g * 16) ^ (l8 << 4)));
                f16x8 vf1 = *(const f16x8*)(vb + (j * 16 + l15) * 128 + ((64 + g * 16) ^ (l8 << 4)));
                #pragma unroll
                for (int qs = 0; qs < 2; qs++) {
                    f32x4 aj = acc[qs][j];
                    #pragma unroll
                    for (int r = 0; r < 4; r++) aj[r] *= al[qs][r];
                    aj = __builtin_amdgcn_mfma_f32_16x16x32_f16(pa[qs][0], vf0, aj, 0, 0, 0);
                    aj = __builtin_amdgcn_mfma_f32_16x16x32_f16(pa[qs][1], vf1, aj, 0, 0, 0);
                    acc[qs][j] = aj;
                }
            }
        }

        asm volatile("" ::: "memory");
        __builtin_amdgcn_s_barrier();          // all waves done reading cur
        asm volatile("" ::: "memory");
    }

    float li[2][4];
    #pragma unroll
    for (int qs = 0; qs < 2; qs++)
        #pragma unroll
        for (int r = 0; r < 4; r++) li[qs][r] = __shfl(lrow[qs], g * 4 + r);
    #pragma unroll
    for (int qs = 0; qs < 2; qs++)
        #pragma unroll
        for (int j = 0; j < 4; j++)
            #pragma unroll
            for (int r = 0; r < 4; r++) {
                float y = acc[qs][j][r] / li[qs][r];
                Yb[((size_t)b * T_ + qw + qs * 16 + g * 4 + r) * D_ + h * HD_ + j * 16 + l15] = (f16)y;
            }
}

// ---------------- launch ----------------
extern "C" void kernel_launch(void* const* d_in, const int* in_sizes, int n_in,
                              void* d_out, int out_size, void* d_ws, size_t ws_size,
                              hipStream_t stream) {
    const float* x      = (const float*)d_in[0];
    const float* w_qkv  = (const float*)d_in[1];
    const float* w_out  = (const float*)d_in[2];
    float* out = (float*)d_out;

    char* ws = (char*)d_ws;
    f16* Xb  = (f16*)(ws);                     // [8192][1024]            16.78 MB
    f16* Wqt = (f16*)(ws + 16777216);          // [3072][1024]             6.29 MB
    f16* Wot = (f16*)(ws + 23068672);          // [1024][1024]             2.10 MB
    f16* Qb  = (f16*)(ws + 25165824);          // [B,H,T,HD]              16.78 MB
    f16* Kb  = (f16*)(ws + 41943040);          // [B,H,T,HD]              16.78 MB
    f16* Vt  = (f16*)(ws + 58720256);          // [B,H,HD,T]              16.78 MB
    f16* Yb  = (f16*)(ws + 75497472);          // [8192][1024]            16.78 MB

    cvt_f32_f16<<<2048, 256, 0, stream>>>(x, Xb, (M_ * D_) / 4);
    transpose_cvt<<<dim3(3 * D_ / 32, D_ / 32), dim3(32, 8), 0, stream>>>(w_qkv, Wqt, D_, 3 * D_);
    transpose_cvt<<<dim3(D_ / 32, D_ / 32),     dim3(32, 8), 0, stream>>>(w_out, Wot, D_, D_);

    gemm128<0><<<dim3(3 * D_ / 128, M_ / 128), 256, 0, stream>>>(Xb, Wqt, 3 * D_, Qb, Kb, Vt, nullptr);
    attn_fwd<<<dim3(16, B_ * H_), 256, 0, stream>>>(Qb, Kb, Vt, Yb);
    gemm128<1><<<dim3(D_ / 128, M_ / 128), 256, 0, stream>>>(Yb, Wot, D_, nullptr, nullptr, nullptr, out);
}

// Round 9
// 324.292 us; speedup vs baseline: 2.1770x; 1.2691x over previous
//
#include <hip/hip_runtime.h>
#include <hip/hip_fp16.h>

typedef _Float16 f16;
typedef f16  f16x8 __attribute__((ext_vector_type(8)));
typedef f16  f16x4 __attribute__((ext_vector_type(4)));
typedef float f32x4 __attribute__((ext_vector_type(4)));

#define B_  4
#define T_  2048
#define D_  1024
#define H_  16
#define HD_ 64
#define M_  (B_*T_)   // 8192

__device__ __forceinline__ void gload_lds16(const void* g, void* l) {
    __builtin_amdgcn_global_load_lds((__attribute__((address_space(1))) void*)(g),
                                     (__attribute__((address_space(3))) void*)(l),
                                     16, 0, 0);
}

// ---------------- fp32 -> fp16 convert (vectorized) ----------------
__global__ __launch_bounds__(256) void cvt_f32_f16(const float* __restrict__ in,
                                                   f16* __restrict__ out, int n4) {
    int idx = blockIdx.x * blockDim.x + threadIdx.x;
    int stride = gridDim.x * blockDim.x;
    for (int i = idx; i < n4; i += stride) {
        float4 v = ((const float4*)in)[i];
        f16x4 o;
        o[0] = (f16)v.x; o[1] = (f16)v.y; o[2] = (f16)v.z; o[3] = (f16)v.w;
        ((f16x4*)out)[i] = o;
    }
}

// ---------------- transpose + convert: in [R][C] f32 -> out [C][R] f16 ----------------
__global__ __launch_bounds__(256) void transpose_cvt(const float* __restrict__ in,
                                                     f16* __restrict__ out, int R, int C) {
    __shared__ float tile[32][33];
    int bx = blockIdx.x * 32;   // col (n) base
    int by = blockIdx.y * 32;   // row (k) base
    int tx = threadIdx.x, ty = threadIdx.y;   // 32 x 8
    #pragma unroll
    for (int i = 0; i < 32; i += 8)
        tile[ty + i][tx] = in[(size_t)(by + ty + i) * C + bx + tx];
    __syncthreads();
    #pragma unroll
    for (int i = 0; i < 32; i += 8)
        out[(size_t)(bx + ty + i) * R + by + tx] = (f16)tile[tx][ty + i];
}

// ---------------- 128x128 BT-GEMM (m97 structure), K=1024 fixed ----------------
template<int EPI>
__global__ __launch_bounds__(256) void gemm128(const f16* __restrict__ A,
                                               const f16* __restrict__ Bt, int N,
                                               f16* __restrict__ Qb, f16* __restrict__ Kb,
                                               f16* __restrict__ Vt, float* __restrict__ Cout) {
    __shared__ f16 At[128][32];
    __shared__ f16 Bs[128][32];
    const int tid = threadIdx.x;
    const int lane = tid & 63;
    const int w = tid >> 6;
    const int g = lane >> 4;
    const int l15 = lane & 15;
    const int wr = w >> 1, wc = w & 1;
    const int m0 = blockIdx.y * 128;
    const int n0 = blockIdx.x * 128;
    const int K = 1024;

    f32x4 acc[4][4];
    #pragma unroll
    for (int i = 0; i < 4; i++)
        #pragma unroll
        for (int j = 0; j < 4; j++)
            acc[i][j] = f32x4{0.f, 0.f, 0.f, 0.f};

    for (int k0 = 0; k0 < K; k0 += 32) {
        __syncthreads();
        #pragma unroll
        for (int i = 0; i < 2; i++) {
            int call = w * 2 + i;
            int chunk = call * 64 + lane;
            int r  = chunk >> 2;
            int c8 = (chunk & 3) * 8;
            gload_lds16(&A [(size_t)(m0 + r) * K + k0 + c8], ((char*)&At[0][0]) + (size_t)call * 1024);
            gload_lds16(&Bt[(size_t)(n0 + r) * K + k0 + c8], ((char*)&Bs[0][0]) + (size_t)call * 1024);
        }
        __syncthreads();
        f16x8 a[4], b[4];
        #pragma unroll
        for (int i = 0; i < 4; i++) a[i] = *(const f16x8*)&At[wr * 64 + i * 16 + l15][g * 8];
        #pragma unroll
        for (int j = 0; j < 4; j++) b[j] = *(const f16x8*)&Bs[wc * 64 + j * 16 + l15][g * 8];
        #pragma unroll
        for (int i = 0; i < 4; i++)
            #pragma unroll
            for (int j = 0; j < 4; j++)
                acc[i][j] = __builtin_amdgcn_mfma_f32_16x16x32_f16(a[i], b[j], acc[i][j], 0, 0, 0);
    }

    if (EPI == 0) {
        const int which = n0 >> 10;
        const int nbase = (n0 & 1023) + wc * 64;
        #pragma unroll
        for (int i = 0; i < 4; i++) {
            int m = m0 + wr * 64 + i * 16 + g * 4;
            int bb = m >> 11;
            int t  = m & 2047;
            #pragma unroll
            for (int j = 0; j < 4; j++) {
                int n = nbase + j * 16 + l15;
                int h = n >> 6, d = n & 63;
                #pragma unroll
                for (int r = 0; r < 4; r++) {
                    f16 v = (f16)acc[i][j][r];
                    if      (which == 0) Qb[(((size_t)bb * H_ + h) * T_ + t + r) * HD_ + d] = v;
                    else if (which == 1) Kb[(((size_t)bb * H_ + h) * T_ + t + r) * HD_ + d] = v;
                    else                 Vt[(((size_t)bb * H_ + h) * HD_ + d) * T_ + t + r] = v;
                }
            }
        }
    } else {
        #pragma unroll
        for (int i = 0; i < 4; i++)
            #pragma unroll
            for (int j = 0; j < 4; j++)
                #pragma unroll
                for (int r = 0; r < 4; r++)
                    Cout[(size_t)(m0 + wr * 64 + i * 16 + g * 4 + r) * N + n0 + wc * 64 + j * 16 + l15]
                        = acc[i][j][r];
    }
}

// ---------------- causal flash attention v3 ----------------
// grid (8, B*H), 256 threads. Mirror-pair load balance: block bx does q-block
// 15-bx (heavy) then bx (light) -> uniform 34 K-tiles per block. Per assignment:
// 128 q-rows, wave owns 32. KVBLK=64, K & V^T double-buffered in LDS via
// global_load_lds (counted vmcnt + raw s_barrier), XOR-16B-chunk swizzle.
__global__ __launch_bounds__(256) void attn_fwd(const f16* __restrict__ Qb, const f16* __restrict__ Kb,
                                                const f16* __restrict__ Vt, f16* __restrict__ Yb) {
    __shared__ f16 KsB[2][64][64];   // [buf][key][d]      16 KB
    __shared__ f16 VsB[2][64][64];   // [buf][d][key]      16 KB
    __shared__ f16 PsB[4][32][64];   // [wave][q][key]     16 KB
    const int tid = threadIdx.x;
    const int lane = tid & 63;
    const int w = tid >> 6;
    const int g = lane >> 4;
    const int l15 = lane & 15;
    const int l8 = l15 & 7;
    const int bh = blockIdx.y;
    const int b = bh >> 4, h = bh & 15;
    const int bx = blockIdx.x;                  // 0..7

    const f16* Qp = Qb + (size_t)bh * T_ * HD_;
    const f16* Kp = Kb + (size_t)bh * T_ * HD_;
    const f16* Vp = Vt + (size_t)bh * HD_ * T_;
    const float cf = 0.125f * 1.44269504088896340736f;   // scale * log2(e)

    // stage K[k0..k0+64) and V^T into buf; source pre-swizzled (rule #21), LDS linear
    auto STAGE = [&](int buf, int it) {
        const int k0 = it * 64;
        #pragma unroll
        for (int cc = 0; cc < 2; cc++) {
            int cb = w * 2 + cc;
            int chunk = cb * 64 + lane;
            int row = chunk >> 3;              // key (K) / d (V)
            int sc = (chunk & 7) ^ (row & 7);  // swizzled 16B chunk within 128B row
            gload_lds16(&Kp[(size_t)(k0 + row) * HD_ + sc * 8],
                        (char*)&KsB[buf][0][0] + (size_t)cb * 1024);
            gload_lds16(&Vp[(size_t)row * T_ + k0 + sc * 8],
                        (char*)&VsB[buf][0][0] + (size_t)cb * 1024);
        }
    };

    #pragma unroll 1
    for (int asg = 0; asg < 2; asg++) {
        const int qbl = asg == 0 ? 15 - bx : bx;          // heavy first, then mirror
        const int qw = qbl * 128 + w * 32;
        const int NT = 2 * qbl + 2;                       // 64-key tiles

        // Q fragments (B-operand): qf[qs][dh], col=q=l15, k=d
        f16x8 qf[2][2];
        #pragma unroll
        for (int qs = 0; qs < 2; qs++)
            #pragma unroll
            for (int dh = 0; dh < 2; dh++)
                qf[qs][dh] = *(const f16x8*)&Qp[(size_t)(qw + qs * 16 + l15) * HD_ + dh * 32 + g * 8];

        f32x4 acc[2][4];
        #pragma unroll
        for (int qs = 0; qs < 2; qs++)
            #pragma unroll
            for (int j = 0; j < 4; j++) acc[qs][j] = f32x4{0.f, 0.f, 0.f, 0.f};
        float mrow[2] = {-1e30f, -1e30f}, lrow[2] = {0.f, 0.f};

        STAGE(0, 0);
        for (int it = 0; it < NT; ++it) {
            const int cur = it & 1;
            const int k0 = it * 64;
            if (it + 1 < NT) {
                STAGE(cur ^ 1, it + 1);
                asm volatile("s_waitcnt vmcnt(4)" ::: "memory");   // cur's 4 loads landed
            } else {
                asm volatile("s_waitcnt vmcnt(0)" ::: "memory");
            }
            __builtin_amdgcn_s_barrier();          // all waves' shares of cur resident
            asm volatile("" ::: "memory");

            if (k0 < qw + 32) {                    // wave-uniform: any unmasked key?
                const char* kb = (const char*)&KsB[cur][0][0];
                const char* vb = (const char*)&VsB[cur][0][0];
                char*       pb = (char*)&PsB[w][0][0];

                // S^T = K·Q^T for 64 keys x 32 q
                float s[2][16];
                #pragma unroll
                for (int kk = 0; kk < 4; kk++) {
                    int row = kk * 16 + l15;       // key-local
                    f16x8 kf0 = *(const f16x8*)(kb + row * 128 + ((g * 16) ^ (l8 << 4)));
                    f16x8 kf1 = *(const f16x8*)(kb + row * 128 + ((64 + g * 16) ^ (l8 << 4)));
                    #pragma unroll
                    for (int qs = 0; qs < 2; qs++) {
                        f32x4 st = {0.f, 0.f, 0.f, 0.f};
                        st = __builtin_amdgcn_mfma_f32_16x16x32_f16(kf0, qf[qs][0], st, 0, 0, 0);
                        st = __builtin_amdgcn_mfma_f32_16x16x32_f16(kf1, qf[qs][1], st, 0, 0, 0);
                        int q = qw + qs * 16 + l15;
                        #pragma unroll
                        for (int r = 0; r < 4; r++) {
                            int key = k0 + kk * 16 + g * 4 + r;
                            s[qs][kk * 4 + r] = (key <= q) ? st[r] * cf : -1e30f;
                        }
                    }
                }

                // online softmax per q-subtile (all 64 lanes busy)
                float alpha[2];
                #pragma unroll
                for (int qs = 0; qs < 2; qs++) {
                    float pm = s[qs][0];
                    #pragma unroll
                    for (int u = 1; u < 16; u++) pm = fmaxf(pm, s[qs][u]);
                    pm = fmaxf(pm, __shfl_xor(pm, 16));
                    pm = fmaxf(pm, __shfl_xor(pm, 32));
                    float mnew = fmaxf(mrow[qs], pm);
                    alpha[qs] = exp2f(mrow[qs] - mnew);
                    float ps = 0.f;
                    #pragma unroll
                    for (int u = 0; u < 16; u++) { s[qs][u] = exp2f(s[qs][u] - mnew); ps += s[qs][u]; }
                    ps += __shfl_xor(ps, 16);
                    ps += __shfl_xor(ps, 32);
                    lrow[qs] = lrow[qs] * alpha[qs] + ps;
                    mrow[qs] = mnew;
                    // pack 4 f16 per key-subtile -> swizzled ds_write_b64
                    int prow = qs * 16 + l15;
                    #pragma unroll
                    for (int kk = 0; kk < 4; kk++) {
                        f16x4 pk;
                        #pragma unroll
                        for (int r = 0; r < 4; r++) pk[r] = (f16)s[qs][kk * 4 + r];
                        *(f16x4*)(pb + prow * 128 + ((kk * 32 + g * 8) ^ (l8 << 4))) = pk;
                    }
                }
                asm volatile("s_waitcnt lgkmcnt(0)" ::: "memory");   // wave-local P visible
                __builtin_amdgcn_sched_barrier(0);

                // P fragments (A-operand): row=q=l15, k=key
                f16x8 pa[2][2];
                #pragma unroll
                for (int qs = 0; qs < 2; qs++)
                    #pragma unroll
                    for (int ks = 0; ks < 2; ks++)
                        pa[qs][ks] = *(const f16x8*)(pb + (qs * 16 + l15) * 128 +
                                                     ((ks * 64 + g * 16) ^ (l8 << 4)));

                float al[2][4];
                #pragma unroll
                for (int qs = 0; qs < 2; qs++)
                    #pragma unroll
                    for (int r = 0; r < 4; r++) al[qs][r] = __shfl(alpha[qs], g * 4 + r);

                #pragma unroll
                for (int j = 0; j < 4; j++) {
                    f16x8 vf0 = *(const f16x8*)(vb + (j * 16 + l15) * 128 + ((g * 16) ^ (l8 << 4)));
                    f16x8 vf1 = *(const f16x8*)(vb + (j * 16 + l15) * 128 + ((64 + g * 16) ^ (l8 << 4)));
                    #pragma unroll
                    for (int qs = 0; qs < 2; qs++) {
                        f32x4 aj = acc[qs][j];
                        #pragma unroll
                        for (int r = 0; r < 4; r++) aj[r] *= al[qs][r];
                        aj = __builtin_amdgcn_mfma_f32_16x16x32_f16(pa[qs][0], vf0, aj, 0, 0, 0);
                        aj = __builtin_amdgcn_mfma_f32_16x16x32_f16(pa[qs][1], vf1, aj, 0, 0, 0);
                        acc[qs][j] = aj;
                    }
                }
            }

            asm volatile("" ::: "memory");
            __builtin_amdgcn_s_barrier();          // all waves done reading cur
            asm volatile("" ::: "memory");
        }

        float li[2][4];
        #pragma unroll
        for (int qs = 0; qs < 2; qs++)
            #pragma unroll
            for (int r = 0; r < 4; r++) li[qs][r] = __shfl(lrow[qs], g * 4 + r);
        #pragma unroll
        for (int qs = 0; qs < 2; qs++)
            #pragma unroll
            for (int j = 0; j < 4; j++)
                #pragma unroll
                for (int r = 0; r < 4; r++) {
                    float y = acc[qs][j][r] / li[qs][r];
                    Yb[((size_t)b * T_ + qw + qs * 16 + g * 4 + r) * D_ + h * HD_ + j * 16 + l15] = (f16)y;
                }
    }
}

// ---------------- launch ----------------
extern "C" void kernel_launch(void* const* d_in, const int* in_sizes, int n_in,
                              void* d_out, int out_size, void* d_ws, size_t ws_size,
                              hipStream_t stream) {
    const float* x      = (const float*)d_in[0];
    const float* w_qkv  = (const float*)d_in[1];
    const float* w_out  = (const float*)d_in[2];
    float* out = (float*)d_out;

    char* ws = (char*)d_ws;
    f16* Xb  = (f16*)(ws);                     // [8192][1024]            16.78 MB
    f16* Wqt = (f16*)(ws + 16777216);          // [3072][1024]             6.29 MB
    f16* Wot = (f16*)(ws + 23068672);          // [1024][1024]             2.10 MB
    f16* Qb  = (f16*)(ws + 25165824);          // [B,H,T,HD]              16.78 MB
    f16* Kb  = (f16*)(ws + 41943040);          // [B,H,T,HD]              16.78 MB
    f16* Vt  = (f16*)(ws + 58720256);          // [B,H,HD,T]              16.78 MB
    f16* Yb  = (f16*)(ws + 75497472);          // [8192][1024]            16.78 MB

    cvt_f32_f16<<<2048, 256, 0, stream>>>(x, Xb, (M_ * D_) / 4);
    transpose_cvt<<<dim3(3 * D_ / 32, D_ / 32), dim3(32, 8), 0, stream>>>(w_qkv, Wqt, D_, 3 * D_);
    transpose_cvt<<<dim3(D_ / 32, D_ / 32),     dim3(32, 8), 0, stream>>>(w_out, Wot, D_, D_);

    gemm128<0><<<dim3(3 * D_ / 128, M_ / 128), 256, 0, stream>>>(Xb, Wqt, 3 * D_, Qb, Kb, Vt, nullptr);
    attn_fwd<<<dim3(8, B_ * H_), 256, 0, stream>>>(Qb, Kb, Vt, Yb);
    gemm128<1><<<dim3(D_ / 128, M_ / 128), 256, 0, stream>>>(Yb, Wot, D_, nullptr, nullptr, nullptr, out);
}